// Round 18
// baseline (60.929 us; speedup 1.0000x reference)
//
#include <hip/hip_runtime.h>
#include <math.h>

static constexpr int BLOCK = 256;
static constexpr int WAVES = BLOCK / 64;
static constexpr int KVAL = 4;
static constexpr int TILE = 256;

typedef float f4 __attribute__((ext_vector_type(4)));
typedef int i4 __attribute__((ext_vector_type(4)));
typedef int i2 __attribute__((ext_vector_type(2)));
typedef unsigned int u2v __attribute__((ext_vector_type(2)));

__device__ __forceinline__ void norm3(float x, float y, float z,
                                      float& ox, float& oy, float& oz) {
  float inv = 1.0f / (sqrtf(x * x + y * y + z * z) + 1e-12f);
  ox = x * inv; oy = y * inv; oz = z * inv;
}

template <int NV>
__device__ __forceinline__ void block_reduce(float (&p)[NV]) {
#pragma unroll
  for (int off = 32; off > 0; off >>= 1)
#pragma unroll
    for (int q = 0; q < NV; ++q) p[q] += __shfl_down(p[q], off, 64);
  __shared__ float sm[WAVES][NV];
  int wave = threadIdx.x >> 6, lane = threadIdx.x & 63;
  if (lane == 0)
#pragma unroll
    for (int q = 0; q < NV; ++q) sm[wave][q] = p[q];
  __syncthreads();
  if (threadIdx.x == 0) {
#pragma unroll
    for (int q = 0; q < NV; ++q) {
      float t = 0.f;
#pragma unroll
      for (int w = 1; w < WAVES; ++w) t += sm[w][q];
      p[q] += t;
    }
  }
}

__device__ __forceinline__ void stage_f(float* __restrict__ dst,
                                        const float* __restrict__ src, int nf) {
  int t = threadIdx.x;
  int nf4 = nf >> 2;
  const f4* s4 = (const f4*)src;
  f4* d4 = (f4*)dst;
  for (int i = t; i < nf4; i += BLOCK) d4[i] = s4[i];
  int rem = nf & 3;
  if (t < rem) dst[nf4 * 4 + t] = src[nf4 * 4 + t];
}

__device__ __forceinline__ void stage_rot_pad(float* __restrict__ B,
                                              const float* __restrict__ src,
                                              int cs) {
  int nf4 = 9 * cs;
  const f4* s4 = (const f4*)src;
  for (int i = threadIdx.x; i < nf4; i += BLOCK) {
    f4 x = __builtin_nontemporal_load(s4 + i);
    int vtx = i / 9, r = i - 9 * vtx;
    float* d = B + vtx * 37 + r * 4;
    d[0] = x.x; d[1] = x.y; d[2] = x.z; d[3] = x.w;
  }
}

__device__ __forceinline__ void unpack8(u2v w, float* va, float* vb) {
  va[0] = __builtin_amdgcn_cvt_f32_fp8((int)w.x, 0);
  va[1] = __builtin_amdgcn_cvt_f32_fp8((int)w.x, 1);
  va[2] = __builtin_amdgcn_cvt_f32_fp8((int)w.x, 2);
  vb[0] = __builtin_amdgcn_cvt_f32_fp8((int)w.x, 3);
  vb[1] = __builtin_amdgcn_cvt_f32_fp8((int)w.y, 0);
  vb[2] = __builtin_amdgcn_cvt_f32_fp8((int)w.y, 1);
}

// ---- A: theta/u/v -> fp8 cross-field table (8 B/vertex) --------------------
__global__ __launch_bounds__(BLOCK) void cf_kernel(
    const float* __restrict__ theta, const float* __restrict__ u,
    const float* __restrict__ v, u2v* __restrict__ vavb8, int N) {
  __shared__ float B[1536];
  int t = threadIdx.x;
  long base = (long)blockIdx.x * TILE;
  int cnt = 0;
  if (base < N) { long c = (long)N - base; cnt = c > TILE ? TILE : (int)c; }
  float thv = 0.f;
  if (t < cnt) thv = theta[base + t];
  if (cnt > 0) {
    stage_f(B, u + 3 * base, 3 * cnt);
    stage_f(B + 768, v + 3 * base, 3 * cnt);
  }
  __syncthreads();
  if (t < cnt) {
    float s, c;
    __sincosf(thv, &s, &c);
    float ux = B[3 * t], uy = B[3 * t + 1], uz = B[3 * t + 2];
    float vx = B[768 + 3 * t], vy = B[768 + 3 * t + 1], vz = B[768 + 3 * t + 2];
    float va[3], vb[3];
    norm3(ux * c + vx * s, uy * c + vy * s, uz * c + vz * s, va[0], va[1], va[2]);
    norm3(vx * c - ux * s, vy * c - uy * s, vz * c - uz * s, vb[0], vb[1], vb[2]);
    unsigned int w0 = (unsigned)__builtin_amdgcn_cvt_pk_fp8_f32(va[0], va[1], 0, false);
    w0 = (unsigned)__builtin_amdgcn_cvt_pk_fp8_f32(va[2], vb[0], (int)w0, true);
    unsigned int w1 = (unsigned)__builtin_amdgcn_cvt_pk_fp8_f32(vb[1], vb[2], 0, false);
    u2v o; o.x = w0; o.y = w1;
    __builtin_nontemporal_store(o, &vavb8[base + t]);
  }
}

// ---- B: mega-kernel; even blocks stream, odd blocks gather -----------------
__global__ __launch_bounds__(BLOCK) void mega_kernel(
    const u2v* __restrict__ vavb8, int N,
    const float* __restrict__ pred, const float* __restrict__ pgrad,
    const float* __restrict__ mp, const float* __restrict__ grad,
    const float* __restrict__ H, const float* __restrict__ ngt,
    const float* __restrict__ rot, const i2* __restrict__ nbr2,
    float* __restrict__ part1, float* __restrict__ part2, int nT, int M) {
  __shared__ float B[4736];  // 18.9 KB (max of both bodies)
  int t = threadIdx.x;
  int tile = blockIdx.x >> 1;
  long base = (long)tile * TILE;

  if ((blockIdx.x & 1) == 0) {
    // ======================= streaming body (s1-rest) =======================
    float p[5] = {0.f, 0.f, 0.f, 0.f, 0.f};  // sdf, eik, morse, halign, inter
    int cntM = 0, cntN = 0;
    if (base < M) { long c = (long)M - base; cntM = c > TILE ? TILE : (int)c; }
    if (base < N) { long c = (long)N - base; cntN = c > TILE ? TILE : (int)c; }

    float prv = 0.f, mpv = 0.f;
    u2v ws = u2v{0, 0};
    if (t < cntM) prv = pred[base + t];
    if (t < cntN) { mpv = mp[base + t]; ws = vavb8[base + t]; }
    float va[3], vb[3];
    unpack8(ws, va, vb);

    // phase A1: pgrad -> point eikonal + inter
    if (cntM > 0) stage_f(B, pgrad + 3 * base, 3 * cntM);
    __syncthreads();
    if (t < cntM) {
      float gx = B[3 * t], gy = B[3 * t + 1], gz = B[3 * t + 2];
      p[1] += fabsf(sqrtf(gx * gx + gy * gy + gz * gz) - 1.0f);
      p[4] += __expf(-100.0f * fabsf(prv));
    }
    __syncthreads();
    // phase A2: grad | ngt
    float ng0 = 0.f, ng1 = 0.f, ng2 = 0.f;
    if (cntN > 0) {
      stage_f(B, grad + 3 * base, 3 * cntN);
      stage_f(B + 768, ngt + 3 * base, 3 * cntN);
    }
    __syncthreads();
    if (t < cntN) {
      float gx = B[3 * t], gy = B[3 * t + 1], gz = B[3 * t + 2];
      p[1] += fabsf(sqrtf(gx * gx + gy * gy + gz * gz) - 1.0f);
      p[0] = fabsf(mpv);
      ng0 = B[768 + 3 * t]; ng1 = B[768 + 3 * t + 1]; ng2 = B[768 + 3 * t + 2];
    }
    __syncthreads();
    // phase C: H -> morse + halign (fp8 va/vb)
    if (cntN > 0) stage_f(B, H + 9 * base, 9 * cntN);
    __syncthreads();
    if (t < cntN) {
      float h[9];
#pragma unroll
      for (int q = 0; q < 9; ++q) h[q] = B[9 * t + q];
      p[2] = fabsf(ng0 * h[0] + ng1 * h[3] + ng2 * h[6]) +
             fabsf(ng0 * h[1] + ng1 * h[4] + ng2 * h[7]) +
             fabsf(ng0 * h[2] + ng1 * h[5] + ng2 * h[8]);
      float a0 = va[0] * h[0] + va[1] * h[3] + va[2] * h[6];
      float a1 = va[0] * h[1] + va[1] * h[4] + va[2] * h[7];
      float a2 = va[0] * h[2] + va[1] * h[5] + va[2] * h[8];
      float b0 = vb[0] * h[0] + vb[1] * h[3] + vb[2] * h[6];
      float b1 = vb[0] * h[1] + vb[1] * h[4] + vb[2] * h[7];
      float b2 = vb[0] * h[2] + vb[1] * h[5] + vb[2] * h[8];
      p[3] = fabsf(a1 * va[2] - a2 * va[1]) + fabsf(a2 * va[0] - a0 * va[2]) +
             fabsf(a0 * va[1] - a1 * va[0]) + fabsf(b1 * vb[2] - b2 * vb[1]) +
             fabsf(b2 * vb[0] - b0 * vb[2]) + fabsf(b0 * vb[1] - b1 * vb[0]);
    }
    block_reduce<5>(p);
    if (t == 0) {
#pragma unroll
      for (int q = 0; q < 5; ++q) part1[q * nT + tile] = p[q];
    }
  } else {
    // ========================= gather body (s3) =============================
    int vl = t >> 1;  // local vertex (0..127)
    int h = t & 1;    // half: owns k = 2h, 2h+1
    int cntN = 0;
    if (base < N) { long c = (long)N - base; cntN = c > TILE ? TILE : (int)c; }

    u2v wn[2][2]; u2v ws[2];
#pragma unroll
    for (int sp = 0; sp < 2; ++sp) {
      ws[sp] = u2v{0, 0};
      wn[sp][0] = u2v{0, 0};
      wn[sp][1] = u2v{0, 0};
      int lv = 128 * sp + vl;
      if (lv < cntN) {
        long n = base + lv;
        i2 jj = __builtin_nontemporal_load(&nbr2[2 * n + h]);
        wn[sp][0] = vavb8[jj.x];
        wn[sp][1] = vavb8[jj.y];
        ws[sp] = vavb8[n];
      }
    }

    float nsum = 0.f;
#pragma unroll
    for (int sp = 0; sp < 2; ++sp) {
      int cs = cntN - 128 * sp;
      if (cs < 0) cs = 0;
      if (cs > 128) cs = 128;
      if (cs > 0) stage_rot_pad(B, rot + 36 * (base + 128 * sp), cs);
      __syncthreads();
      if (vl < cs) {
        float va[3], vb[3];
        unpack8(ws[sp], va, vb);
        const float* R0 = B + 37 * vl;
#pragma unroll
        for (int kk = 0; kk < 2; ++kk) {
          int k = 2 * h + kk;
          float R[9];
#pragma unroll
          for (int q = 0; q < 9; ++q) R[q] = R0[9 * k + q];
          float pa0 = R[0] * va[0] + R[3] * va[1] + R[6] * va[2];
          float pa1 = R[1] * va[0] + R[4] * va[1] + R[7] * va[2];
          float pa2 = R[2] * va[0] + R[5] * va[1] + R[8] * va[2];
          float pb0 = R[0] * vb[0] + R[3] * vb[1] + R[6] * vb[2];
          float pb1 = R[1] * vb[0] + R[4] * vb[1] + R[7] * vb[2];
          float pb2 = R[2] * vb[0] + R[5] * vb[1] + R[8] * vb[2];
          float aj[3], bj[3];
          unpack8(wn[sp][kk], aj, bj);
          nsum += fabsf(pa0 * aj[0] + pa1 * aj[1] + pa2 * aj[2]) +
                  fabsf(pa0 * bj[0] + pa1 * bj[1] + pa2 * bj[2]) +
                  fabsf(pb0 * aj[0] + pb1 * aj[1] + pb2 * aj[2]) +
                  fabsf(pb0 * bj[0] + pb1 * bj[1] + pb2 * bj[2]) - 2.0f;
        }
      }
      __syncthreads();
    }
    float p[1] = {nsum};
    block_reduce<1>(p);
    if (t == 0) part2[tile] = p[0];
  }
}

// ---- finalize ---------------------------------------------------------------
__global__ __launch_bounds__(BLOCK) void finalize_fast(
    const float* __restrict__ part1, const float* __restrict__ part2, int nT,
    float* __restrict__ out, int N, int M) {
  float s[6] = {0.f, 0.f, 0.f, 0.f, 0.f, 0.f};
  for (int b = threadIdx.x; b < nT; b += BLOCK) {
#pragma unroll
    for (int q = 0; q < 5; ++q) s[q] += part1[q * nT + b];
    s[5] += part2[b];
  }
  block_reduce<6>(s);
  if (threadIdx.x == 0) {
    float sdf = s[0] / (float)N;
    float eik = s[1] / (float)(N + M);
    float morse = 0.5f * s[2] / (3.0f * (float)N);
    float th = 0.5f * s[3] / (3.0f * (float)N);
    float inter = s[4] / (float)M;
    float nb = s[5] / ((float)N * (float)KVAL);
    float loss = 7000.0f * sdf + 600.0f * inter + 50.0f * eik + 3.0f * morse +
                 10.0f * th + 30.0f * nb;
    out[0] = loss; out[1] = sdf; out[2] = inter; out[3] = eik;
    out[4] = morse; out[5] = th; out[6] = nb;
  }
}

// ---------------- fallback path (atomics, no ws tables) ---------------------
__device__ __forceinline__ void crossfield(const float* __restrict__ u,
                                           const float* __restrict__ v,
                                           const float* __restrict__ theta,
                                           int n, float va[3], float vb[3]) {
  float s, c;
  __sincosf(theta[n], &s, &c);
  float ux = u[3 * n], uy = u[3 * n + 1], uz = u[3 * n + 2];
  float vx = v[3 * n], vy = v[3 * n + 1], vz = v[3 * n + 2];
  norm3(ux * c + vx * s, uy * c + vy * s, uz * c + vz * s, va[0], va[1], va[2]);
  norm3(vx * c - ux * s, vy * c - uy * s, vz * c - uz * s, vb[0], vb[1], vb[2]);
}

__global__ __launch_bounds__(BLOCK) void vertex_kernel(
    const float* __restrict__ mp, const float* __restrict__ grad,
    const float* __restrict__ H, const float* __restrict__ ngt,
    const float* __restrict__ theta, const float* __restrict__ u,
    const float* __restrict__ v, const float* __restrict__ rot,
    const int* __restrict__ nbr, float* __restrict__ acc, int N) {
  int n = blockIdx.x * blockDim.x + threadIdx.x;
  float p[5] = {0.f, 0.f, 0.f, 0.f, 0.f};
  if (n < N) {
    float hh[9];
#pragma unroll
    for (int i = 0; i < 9; ++i) hh[i] = H[9 * (size_t)n + i];
    p[0] = fabsf(mp[n]);
    float gx = grad[3 * n], gy = grad[3 * n + 1], gz = grad[3 * n + 2];
    p[1] = fabsf(sqrtf(gx * gx + gy * gy + gz * gz) - 1.0f);
    float n0 = ngt[3 * n], n1 = ngt[3 * n + 1], n2 = ngt[3 * n + 2];
    p[2] = fabsf(n0 * hh[0] + n1 * hh[3] + n2 * hh[6]) +
           fabsf(n0 * hh[1] + n1 * hh[4] + n2 * hh[7]) +
           fabsf(n0 * hh[2] + n1 * hh[5] + n2 * hh[8]);
    float va[3], vb[3];
    crossfield(u, v, theta, n, va, vb);
    {
      float a0 = va[0] * hh[0] + va[1] * hh[3] + va[2] * hh[6];
      float a1 = va[0] * hh[1] + va[1] * hh[4] + va[2] * hh[7];
      float a2 = va[0] * hh[2] + va[1] * hh[5] + va[2] * hh[8];
      float b0 = vb[0] * hh[0] + vb[1] * hh[3] + vb[2] * hh[6];
      float b1 = vb[0] * hh[1] + vb[1] * hh[4] + vb[2] * hh[7];
      float b2 = vb[0] * hh[2] + vb[1] * hh[5] + vb[2] * hh[8];
      p[3] = fabsf(a1 * va[2] - a2 * va[1]) + fabsf(a2 * va[0] - a0 * va[2]) +
             fabsf(a0 * va[1] - a1 * va[0]) + fabsf(b1 * vb[2] - b2 * vb[1]) +
             fabsf(b2 * vb[0] - b0 * vb[2]) + fabsf(b0 * vb[1] - b1 * vb[0]);
    }
    float nsum = 0.f;
    const float* R = rot + (size_t)n * (KVAL * 9);
#pragma unroll
    for (int k = 0; k < KVAL; ++k) {
      int j = nbr[KVAL * (size_t)n + k];
      float vaj[3], vbj[3];
      crossfield(u, v, theta, j, vaj, vbj);
      float r0 = R[9 * k + 0], r1 = R[9 * k + 1], r2 = R[9 * k + 2];
      float r3 = R[9 * k + 3], r4 = R[9 * k + 4], r5 = R[9 * k + 5];
      float r6 = R[9 * k + 6], r7 = R[9 * k + 7], r8 = R[9 * k + 8];
      float wa0 = r0 * vaj[0] + r1 * vaj[1] + r2 * vaj[2];
      float wa1 = r3 * vaj[0] + r4 * vaj[1] + r5 * vaj[2];
      float wa2 = r6 * vaj[0] + r7 * vaj[1] + r8 * vaj[2];
      float wb0 = r0 * vbj[0] + r1 * vbj[1] + r2 * vbj[2];
      float wb1 = r3 * vbj[0] + r4 * vbj[1] + r5 * vbj[2];
      float wb2 = r6 * vbj[0] + r7 * vbj[1] + r8 * vbj[2];
      nsum += fabsf(va[0] * wa0 + va[1] * wa1 + va[2] * wa2) +
              fabsf(va[0] * wb0 + va[1] * wb1 + va[2] * wb2) +
              fabsf(vb[0] * wa0 + vb[1] * wa1 + vb[2] * wa2) +
              fabsf(vb[0] * wb0 + vb[1] * wb1 + vb[2] * wb2) - 2.0f;
    }
    p[4] = nsum;
  }
  block_reduce<5>(p);
  if (threadIdx.x == 0) {
    atomicAdd(&acc[0], p[0]); atomicAdd(&acc[1], p[1]); atomicAdd(&acc[2], p[2]);
    atomicAdd(&acc[3], p[3]); atomicAdd(&acc[4], p[4]);
  }
}

__global__ __launch_bounds__(BLOCK) void point_kernel(
    const float* __restrict__ pred, const float* __restrict__ grad,
    float* __restrict__ acc, int M) {
  int i = blockIdx.x * blockDim.x + threadIdx.x;
  float p[2] = {0.f, 0.f};
  if (i < M) {
    p[0] = __expf(-100.0f * fabsf(pred[i]));
    float gx = grad[3 * i], gy = grad[3 * i + 1], gz = grad[3 * i + 2];
    p[1] = fabsf(sqrtf(gx * gx + gy * gy + gz * gz) - 1.0f);
  }
  block_reduce<2>(p);
  if (threadIdx.x == 0) {
    atomicAdd(&acc[5], p[0]); atomicAdd(&acc[1], p[1]);
  }
}

__global__ void finalize_acc(const float* __restrict__ acc, float* __restrict__ out,
                             int N, int M) {
  if (threadIdx.x == 0 && blockIdx.x == 0) {
    float sdf = acc[0] / (float)N;
    float eik = acc[1] / (float)(N + M);
    float morse = 0.5f * acc[2] / (3.0f * (float)N);
    float th = 0.5f * acc[3] / (3.0f * (float)N);
    float nb = acc[4] / ((float)N * (float)KVAL);
    float inter = acc[5] / (float)M;
    float loss = 7000.0f * sdf + 600.0f * inter + 50.0f * eik + 3.0f * morse +
                 10.0f * th + 30.0f * nb;
    out[0] = loss; out[1] = sdf; out[2] = inter; out[3] = eik;
    out[4] = morse; out[5] = th; out[6] = nb;
  }
}

extern "C" void kernel_launch(void* const* d_in, const int* in_sizes, int n_in,
                              void* d_out, int out_size, void* d_ws, size_t ws_size,
                              hipStream_t stream) {
  const float* mp    = (const float*)d_in[0];
  const float* npred = (const float*)d_in[1];
  const float* grad  = (const float*)d_in[2];
  const float* ngrad = (const float*)d_in[3];
  const float* H     = (const float*)d_in[4];
  const float* ngt   = (const float*)d_in[5];
  const float* theta = (const float*)d_in[6];
  const float* u     = (const float*)d_in[7];
  const float* v     = (const float*)d_in[8];
  const float* rot   = (const float*)d_in[9];
  const int*   nbr   = (const int*)d_in[10];
  float* out = (float*)d_out;

  int N = in_sizes[0];
  int M = in_sizes[1];
  int mx = (N > M) ? N : M;
  int nT = (mx + TILE - 1) / TILE;   // tiles for both bodies
  int nbN = (N + TILE - 1) / TILE;   // cf blocks

  size_t off_vavb = 256;
  size_t off_p1 = off_vavb + (size_t)N * 8;
  size_t off_p2 = off_p1 + (size_t)5 * nT * 4;
  size_t need = off_p2 + (size_t)nT * 4;

  if (ws_size >= need) {
    u2v* vavb8   = (u2v*)((char*)d_ws + off_vavb);
    float* part1 = (float*)((char*)d_ws + off_p1);
    float* part2 = (float*)((char*)d_ws + off_p2);
    cf_kernel<<<nbN, BLOCK, 0, stream>>>(theta, u, v, vavb8, N);
    mega_kernel<<<2 * nT, BLOCK, 0, stream>>>(
        vavb8, N, npred, ngrad, mp, grad, H, ngt, rot, (const i2*)nbr,
        part1, part2, nT, M);
    finalize_fast<<<1, BLOCK, 0, stream>>>(part1, part2, nT, out, N, M);
  } else {
    float* acc = (float*)d_ws;
    (void)hipMemsetAsync(acc, 0, 6 * sizeof(float), stream);
    vertex_kernel<<<(N + BLOCK - 1) / BLOCK, BLOCK, 0, stream>>>(
        mp, grad, H, ngt, theta, u, v, rot, nbr, acc, N);
    point_kernel<<<(M + BLOCK - 1) / BLOCK, BLOCK, 0, stream>>>(npred, ngrad, acc, M);
    finalize_acc<<<1, 64, 0, stream>>>(acc, out, N, M);
  }
}

// Round 19
// 51.149 us; speedup vs baseline: 1.1912x; 1.1912x over previous
//
#include <hip/hip_runtime.h>
#include <math.h>

static constexpr int BLOCK = 256;
static constexpr int WAVES = BLOCK / 64;
static constexpr int KVAL = 4;
static constexpr int TILE = 256;

typedef float f4 __attribute__((ext_vector_type(4)));
typedef int i4 __attribute__((ext_vector_type(4)));
typedef int i2 __attribute__((ext_vector_type(2)));
typedef unsigned int u2v __attribute__((ext_vector_type(2)));

__device__ __forceinline__ void norm3(float x, float y, float z,
                                      float& ox, float& oy, float& oz) {
  float inv = 1.0f / (sqrtf(x * x + y * y + z * z) + 1e-12f);
  ox = x * inv; oy = y * inv; oz = z * inv;
}

template <int NV>
__device__ __forceinline__ void block_reduce(float (&p)[NV]) {
#pragma unroll
  for (int off = 32; off > 0; off >>= 1)
#pragma unroll
    for (int q = 0; q < NV; ++q) p[q] += __shfl_down(p[q], off, 64);
  __shared__ float sm[WAVES][NV];
  int wave = threadIdx.x >> 6, lane = threadIdx.x & 63;
  if (lane == 0)
#pragma unroll
    for (int q = 0; q < NV; ++q) sm[wave][q] = p[q];
  __syncthreads();
  if (threadIdx.x == 0) {
#pragma unroll
    for (int q = 0; q < NV; ++q) {
      float t = 0.f;
#pragma unroll
      for (int w = 1; w < WAVES; ++w) t += sm[w][q];
      p[q] += t;
    }
  }
}

__device__ __forceinline__ void stage_f(float* __restrict__ dst,
                                        const float* __restrict__ src, int nf) {
  int t = threadIdx.x;
  int nf4 = nf >> 2;
  const f4* s4 = (const f4*)src;
  f4* d4 = (f4*)dst;
  for (int i = t; i < nf4; i += BLOCK) d4[i] = s4[i];
  int rem = nf & 3;
  if (t < rem) dst[nf4 * 4 + t] = src[nf4 * 4 + t];
}

// stage cs vertices' rot into padded LDS (stride 37 floats), nontemporal reads
__device__ __forceinline__ void stage_rot_pad(float* __restrict__ B,
                                              const float* __restrict__ src,
                                              int cs) {
  int nf4 = 9 * cs;
  const f4* s4 = (const f4*)src;
  for (int i = threadIdx.x; i < nf4; i += BLOCK) {
    f4 x = __builtin_nontemporal_load(s4 + i);
    int vtx = i / 9, r = i - 9 * vtx;
    float* d = B + vtx * 37 + r * 4;
    d[0] = x.x; d[1] = x.y; d[2] = x.z; d[3] = x.w;
  }
}

// unpack 6 x fp8 (bytes: va0 va1 va2 vb0 | vb1 vb2 - -) -> floats
__device__ __forceinline__ void unpack8(u2v w, float* va, float* vb) {
  va[0] = __builtin_amdgcn_cvt_f32_fp8((int)w.x, 0);
  va[1] = __builtin_amdgcn_cvt_f32_fp8((int)w.x, 1);
  va[2] = __builtin_amdgcn_cvt_f32_fp8((int)w.x, 2);
  vb[0] = __builtin_amdgcn_cvt_f32_fp8((int)w.x, 3);
  vb[1] = __builtin_amdgcn_cvt_f32_fp8((int)w.y, 0);
  vb[2] = __builtin_amdgcn_cvt_f32_fp8((int)w.y, 1);
}

// ---- S1: streaming terms; writes fp8-packed vavb (8 B/vertex) --------------
__global__ __launch_bounds__(BLOCK) void s1_kernel(
    const float* __restrict__ theta, const float* __restrict__ u,
    const float* __restrict__ v, u2v* __restrict__ vavb8, int N,
    const float* __restrict__ pred, const float* __restrict__ pgrad,
    const float* __restrict__ mp, const float* __restrict__ grad,
    const float* __restrict__ H, const float* __restrict__ ngt,
    float* __restrict__ part1, int nb1, int M) {
  __shared__ float B[2304];
  int t = threadIdx.x;
  long base = (long)blockIdx.x * TILE;
  float p[5] = {0.f, 0.f, 0.f, 0.f, 0.f};  // sdf, eik, morse, halign, inter

  int cntM = 0, cntN = 0;
  if (base < M) { long c = (long)M - base; cntM = c > TILE ? TILE : (int)c; }
  if (base < N) { long c = (long)N - base; cntN = c > TILE ? TILE : (int)c; }

  float prv = 0.f, mpv = 0.f, thv = 0.f;
  if (t < cntM) prv = pred[base + t];
  if (t < cntN) { mpv = mp[base + t]; thv = theta[base + t]; }

  // ---- phase A: pgrad, then grad | ngt
  if (cntM > 0) stage_f(B, pgrad + 3 * base, 3 * cntM);
  __syncthreads();
  if (t < cntM) {
    float gx = B[3 * t], gy = B[3 * t + 1], gz = B[3 * t + 2];
    p[1] += fabsf(sqrtf(gx * gx + gy * gy + gz * gz) - 1.0f);
    p[4] += __expf(-100.0f * fabsf(prv));
  }
  __syncthreads();
  float ng0 = 0.f, ng1 = 0.f, ng2 = 0.f;
  if (cntN > 0) {
    stage_f(B, grad + 3 * base, 3 * cntN);
    stage_f(B + 768, ngt + 3 * base, 3 * cntN);
  }
  __syncthreads();
  if (t < cntN) {
    float gx = B[3 * t], gy = B[3 * t + 1], gz = B[3 * t + 2];
    p[1] += fabsf(sqrtf(gx * gx + gy * gy + gz * gz) - 1.0f);
    p[0] = fabsf(mpv);
    ng0 = B[768 + 3 * t]; ng1 = B[768 + 3 * t + 1]; ng2 = B[768 + 3 * t + 2];
  }
  __syncthreads();

  // ---- phase B: u | v -> crossfield, write fp8 vavb
  if (cntN > 0) {
    stage_f(B, u + 3 * base, 3 * cntN);
    stage_f(B + 768, v + 3 * base, 3 * cntN);
  }
  __syncthreads();
  float va[3] = {0.f, 0.f, 0.f}, vb[3] = {0.f, 0.f, 0.f};
  if (t < cntN) {
    float s, c;
    __sincosf(thv, &s, &c);
    float ux = B[3 * t], uy = B[3 * t + 1], uz = B[3 * t + 2];
    float vx = B[768 + 3 * t], vy = B[768 + 3 * t + 1], vz = B[768 + 3 * t + 2];
    norm3(ux * c + vx * s, uy * c + vy * s, uz * c + vz * s, va[0], va[1], va[2]);
    norm3(vx * c - ux * s, vy * c - uy * s, vz * c - uz * s, vb[0], vb[1], vb[2]);
    unsigned int w0 = (unsigned)__builtin_amdgcn_cvt_pk_fp8_f32(va[0], va[1], 0, false);
    w0 = (unsigned)__builtin_amdgcn_cvt_pk_fp8_f32(va[2], vb[0], (int)w0, true);
    unsigned int w1 = (unsigned)__builtin_amdgcn_cvt_pk_fp8_f32(vb[1], vb[2], 0, false);
    u2v o; o.x = w0; o.y = w1;
    __builtin_nontemporal_store(o, &vavb8[base + t]);
  }
  __syncthreads();

  // ---- phase C: H -> morse + hessian alignment (exact f32 va/vb)
  if (cntN > 0) stage_f(B, H + 9 * base, 9 * cntN);
  __syncthreads();
  if (t < cntN) {
    float h[9];
#pragma unroll
    for (int q = 0; q < 9; ++q) h[q] = B[9 * t + q];
    p[2] = fabsf(ng0 * h[0] + ng1 * h[3] + ng2 * h[6]) +
           fabsf(ng0 * h[1] + ng1 * h[4] + ng2 * h[7]) +
           fabsf(ng0 * h[2] + ng1 * h[5] + ng2 * h[8]);
    float a0 = va[0] * h[0] + va[1] * h[3] + va[2] * h[6];
    float a1 = va[0] * h[1] + va[1] * h[4] + va[2] * h[7];
    float a2 = va[0] * h[2] + va[1] * h[5] + va[2] * h[8];
    float b0 = vb[0] * h[0] + vb[1] * h[3] + vb[2] * h[6];
    float b1 = vb[0] * h[1] + vb[1] * h[4] + vb[2] * h[7];
    float b2 = vb[0] * h[2] + vb[1] * h[5] + vb[2] * h[8];
    p[3] = fabsf(a1 * va[2] - a2 * va[1]) + fabsf(a2 * va[0] - a0 * va[2]) +
           fabsf(a0 * va[1] - a1 * va[0]) + fabsf(b1 * vb[2] - b2 * vb[1]) +
           fabsf(b2 * vb[0] - b0 * vb[2]) + fabsf(b0 * vb[1] - b1 * vb[0]);
  }

  block_reduce<5>(p);
  if (t == 0) {
#pragma unroll
    for (int q = 0; q < 5; ++q) part1[q * nb1 + blockIdx.x] = p[q];
  }
}

// ---- S3: neighbor consistency; fp8 gathers (L2-resident 4 MB table) --------
__global__ __launch_bounds__(BLOCK) void s3_kernel(
    const u2v* __restrict__ vavb8, const float* __restrict__ rot,
    const i2* __restrict__ nbr2, float* __restrict__ part2, int N) {
  __shared__ float B[128 * 37];  // 18.9 KB
  int t = threadIdx.x;
  int vl = t >> 1;  // local vertex (0..127)
  int h = t & 1;    // half: owns k = 2h, 2h+1
  long base = (long)blockIdx.x * TILE;
  int cntN = 0;
  if (base < N) { long c = (long)N - base; cntN = c > TILE ? TILE : (int)c; }

  // issue all scattered loads for both sub-tiles upfront (cacheable - want L2)
  u2v wn[2][2]; u2v ws[2];
#pragma unroll
  for (int sp = 0; sp < 2; ++sp) {
    ws[sp] = u2v{0, 0};
    wn[sp][0] = u2v{0, 0};
    wn[sp][1] = u2v{0, 0};
    int lv = 128 * sp + vl;
    if (lv < cntN) {
      long n = base + lv;
      i2 jj = __builtin_nontemporal_load(&nbr2[2 * n + h]);
      wn[sp][0] = vavb8[jj.x];
      wn[sp][1] = vavb8[jj.y];
      ws[sp] = vavb8[n];
    }
  }

  float nsum = 0.f;
#pragma unroll
  for (int sp = 0; sp < 2; ++sp) {
    int cs = cntN - 128 * sp;
    if (cs < 0) cs = 0;
    if (cs > 128) cs = 128;
    if (cs > 0) stage_rot_pad(B, rot + 36 * (base + 128 * sp), cs);
    __syncthreads();
    if (vl < cs) {
      float va[3], vb[3];
      unpack8(ws[sp], va, vb);
      const float* R0 = B + 37 * vl;
#pragma unroll
      for (int kk = 0; kk < 2; ++kk) {
        int k = 2 * h + kk;
        float R[9];
#pragma unroll
        for (int q = 0; q < 9; ++q) R[q] = R0[9 * k + q];
        float pa0 = R[0] * va[0] + R[3] * va[1] + R[6] * va[2];
        float pa1 = R[1] * va[0] + R[4] * va[1] + R[7] * va[2];
        float pa2 = R[2] * va[0] + R[5] * va[1] + R[8] * va[2];
        float pb0 = R[0] * vb[0] + R[3] * vb[1] + R[6] * vb[2];
        float pb1 = R[1] * vb[0] + R[4] * vb[1] + R[7] * vb[2];
        float pb2 = R[2] * vb[0] + R[5] * vb[1] + R[8] * vb[2];
        float aj[3], bj[3];
        unpack8(wn[sp][kk], aj, bj);
        nsum += fabsf(pa0 * aj[0] + pa1 * aj[1] + pa2 * aj[2]) +
                fabsf(pa0 * bj[0] + pa1 * bj[1] + pa2 * bj[2]) +
                fabsf(pb0 * aj[0] + pb1 * aj[1] + pb2 * aj[2]) +
                fabsf(pb0 * bj[0] + pb1 * bj[1] + pb2 * bj[2]) - 2.0f;
      }
    }
    __syncthreads();
  }
  float p[1] = {nsum};
  block_reduce<1>(p);
  if (t == 0) part2[blockIdx.x] = p[0];
}

// ---- finalize ---------------------------------------------------------------
__global__ __launch_bounds__(BLOCK) void finalize_fast(
    const float* __restrict__ part1, int nb1, const float* __restrict__ part2,
    int nb2, float* __restrict__ out, int N, int M) {
  float s[6] = {0.f, 0.f, 0.f, 0.f, 0.f, 0.f};
  for (int b = threadIdx.x; b < nb1; b += BLOCK) {
#pragma unroll
    for (int q = 0; q < 5; ++q) s[q] += part1[q * nb1 + b];
  }
  for (int b = threadIdx.x; b < nb2; b += BLOCK) s[5] += part2[b];
  block_reduce<6>(s);
  if (threadIdx.x == 0) {
    float sdf = s[0] / (float)N;
    float eik = s[1] / (float)(N + M);
    float morse = 0.5f * s[2] / (3.0f * (float)N);
    float th = 0.5f * s[3] / (3.0f * (float)N);
    float inter = s[4] / (float)M;
    float nb = s[5] / ((float)N * (float)KVAL);
    float loss = 7000.0f * sdf + 600.0f * inter + 50.0f * eik + 3.0f * morse +
                 10.0f * th + 30.0f * nb;
    out[0] = loss; out[1] = sdf; out[2] = inter; out[3] = eik;
    out[4] = morse; out[5] = th; out[6] = nb;
  }
}

// ---------------- fallback path (atomics, no ws tables) ---------------------
__device__ __forceinline__ void crossfield(const float* __restrict__ u,
                                           const float* __restrict__ v,
                                           const float* __restrict__ theta,
                                           int n, float va[3], float vb[3]) {
  float s, c;
  __sincosf(theta[n], &s, &c);
  float ux = u[3 * n], uy = u[3 * n + 1], uz = u[3 * n + 2];
  float vx = v[3 * n], vy = v[3 * n + 1], vz = v[3 * n + 2];
  norm3(ux * c + vx * s, uy * c + vy * s, uz * c + vz * s, va[0], va[1], va[2]);
  norm3(vx * c - ux * s, vy * c - uy * s, vz * c - uz * s, vb[0], vb[1], vb[2]);
}

__global__ __launch_bounds__(BLOCK) void vertex_kernel(
    const float* __restrict__ mp, const float* __restrict__ grad,
    const float* __restrict__ H, const float* __restrict__ ngt,
    const float* __restrict__ theta, const float* __restrict__ u,
    const float* __restrict__ v, const float* __restrict__ rot,
    const int* __restrict__ nbr, float* __restrict__ acc, int N) {
  int n = blockIdx.x * blockDim.x + threadIdx.x;
  float p[5] = {0.f, 0.f, 0.f, 0.f, 0.f};
  if (n < N) {
    float hh[9];
#pragma unroll
    for (int i = 0; i < 9; ++i) hh[i] = H[9 * (size_t)n + i];
    p[0] = fabsf(mp[n]);
    float gx = grad[3 * n], gy = grad[3 * n + 1], gz = grad[3 * n + 2];
    p[1] = fabsf(sqrtf(gx * gx + gy * gy + gz * gz) - 1.0f);
    float n0 = ngt[3 * n], n1 = ngt[3 * n + 1], n2 = ngt[3 * n + 2];
    p[2] = fabsf(n0 * hh[0] + n1 * hh[3] + n2 * hh[6]) +
           fabsf(n0 * hh[1] + n1 * hh[4] + n2 * hh[7]) +
           fabsf(n0 * hh[2] + n1 * hh[5] + n2 * hh[8]);
    float va[3], vb[3];
    crossfield(u, v, theta, n, va, vb);
    {
      float a0 = va[0] * hh[0] + va[1] * hh[3] + va[2] * hh[6];
      float a1 = va[0] * hh[1] + va[1] * hh[4] + va[2] * hh[7];
      float a2 = va[0] * hh[2] + va[1] * hh[5] + va[2] * hh[8];
      float b0 = vb[0] * hh[0] + vb[1] * hh[3] + vb[2] * hh[6];
      float b1 = vb[0] * hh[1] + vb[1] * hh[4] + vb[2] * hh[7];
      float b2 = vb[0] * hh[2] + vb[1] * hh[5] + vb[2] * hh[8];
      p[3] = fabsf(a1 * va[2] - a2 * va[1]) + fabsf(a2 * va[0] - a0 * va[2]) +
             fabsf(a0 * va[1] - a1 * va[0]) + fabsf(b1 * vb[2] - b2 * vb[1]) +
             fabsf(b2 * vb[0] - b0 * vb[2]) + fabsf(b0 * vb[1] - b1 * vb[0]);
    }
    float nsum = 0.f;
    const float* R = rot + (size_t)n * (KVAL * 9);
#pragma unroll
    for (int k = 0; k < KVAL; ++k) {
      int j = nbr[KVAL * (size_t)n + k];
      float vaj[3], vbj[3];
      crossfield(u, v, theta, j, vaj, vbj);
      float r0 = R[9 * k + 0], r1 = R[9 * k + 1], r2 = R[9 * k + 2];
      float r3 = R[9 * k + 3], r4 = R[9 * k + 4], r5 = R[9 * k + 5];
      float r6 = R[9 * k + 6], r7 = R[9 * k + 7], r8 = R[9 * k + 8];
      float wa0 = r0 * vaj[0] + r1 * vaj[1] + r2 * vaj[2];
      float wa1 = r3 * vaj[0] + r4 * vaj[1] + r5 * vaj[2];
      float wa2 = r6 * vaj[0] + r7 * vaj[1] + r8 * vaj[2];
      float wb0 = r0 * vbj[0] + r1 * vbj[1] + r2 * vbj[2];
      float wb1 = r3 * vbj[0] + r4 * vbj[1] + r5 * vbj[2];
      float wb2 = r6 * vbj[0] + r7 * vbj[1] + r8 * vbj[2];
      nsum += fabsf(va[0] * wa0 + va[1] * wa1 + va[2] * wa2) +
              fabsf(va[0] * wb0 + va[1] * wb1 + va[2] * wb2) +
              fabsf(vb[0] * wa0 + vb[1] * wa1 + vb[2] * wa2) +
              fabsf(vb[0] * wb0 + vb[1] * wb1 + vb[2] * wb2) - 2.0f;
    }
    p[4] = nsum;
  }
  block_reduce<5>(p);
  if (threadIdx.x == 0) {
    atomicAdd(&acc[0], p[0]); atomicAdd(&acc[1], p[1]); atomicAdd(&acc[2], p[2]);
    atomicAdd(&acc[3], p[3]); atomicAdd(&acc[4], p[4]);
  }
}

__global__ __launch_bounds__(BLOCK) void point_kernel(
    const float* __restrict__ pred, const float* __restrict__ grad,
    float* __restrict__ acc, int M) {
  int i = blockIdx.x * blockDim.x + threadIdx.x;
  float p[2] = {0.f, 0.f};
  if (i < M) {
    p[0] = __expf(-100.0f * fabsf(pred[i]));
    float gx = grad[3 * i], gy = grad[3 * i + 1], gz = grad[3 * i + 2];
    p[1] = fabsf(sqrtf(gx * gx + gy * gy + gz * gz) - 1.0f);
  }
  block_reduce<2>(p);
  if (threadIdx.x == 0) {
    atomicAdd(&acc[5], p[0]); atomicAdd(&acc[1], p[1]);
  }
}

__global__ void finalize_acc(const float* __restrict__ acc, float* __restrict__ out,
                             int N, int M) {
  if (threadIdx.x == 0 && blockIdx.x == 0) {
    float sdf = acc[0] / (float)N;
    float eik = acc[1] / (float)(N + M);
    float morse = 0.5f * acc[2] / (3.0f * (float)N);
    float th = 0.5f * acc[3] / (3.0f * (float)N);
    float nb = acc[4] / ((float)N * (float)KVAL);
    float inter = acc[5] / (float)M;
    float loss = 7000.0f * sdf + 600.0f * inter + 50.0f * eik + 3.0f * morse +
                 10.0f * th + 30.0f * nb;
    out[0] = loss; out[1] = sdf; out[2] = inter; out[3] = eik;
    out[4] = morse; out[5] = th; out[6] = nb;
  }
}

extern "C" void kernel_launch(void* const* d_in, const int* in_sizes, int n_in,
                              void* d_out, int out_size, void* d_ws, size_t ws_size,
                              hipStream_t stream) {
  const float* mp    = (const float*)d_in[0];
  const float* npred = (const float*)d_in[1];
  const float* grad  = (const float*)d_in[2];
  const float* ngrad = (const float*)d_in[3];
  const float* H     = (const float*)d_in[4];
  const float* ngt   = (const float*)d_in[5];
  const float* theta = (const float*)d_in[6];
  const float* u     = (const float*)d_in[7];
  const float* v     = (const float*)d_in[8];
  const float* rot   = (const float*)d_in[9];
  const int*   nbr   = (const int*)d_in[10];
  float* out = (float*)d_out;

  int N = in_sizes[0];
  int M = in_sizes[1];
  int mx = (N > M) ? N : M;
  int nb1 = (mx + TILE - 1) / TILE;
  int nb2 = (N + TILE - 1) / TILE;

  size_t off_vavb = 256;
  size_t off_p1 = off_vavb + (size_t)N * 8;
  size_t off_p2 = off_p1 + (size_t)5 * nb1 * 4;
  size_t need = off_p2 + (size_t)nb2 * 4;

  if (ws_size >= need) {
    u2v* vavb8   = (u2v*)((char*)d_ws + off_vavb);
    float* part1 = (float*)((char*)d_ws + off_p1);
    float* part2 = (float*)((char*)d_ws + off_p2);
    s1_kernel<<<nb1, BLOCK, 0, stream>>>(
        theta, u, v, vavb8, N, npred, ngrad, mp, grad, H, ngt, part1, nb1, M);
    s3_kernel<<<nb2, BLOCK, 0, stream>>>(
        vavb8, rot, (const i2*)nbr, part2, N);
    finalize_fast<<<1, BLOCK, 0, stream>>>(part1, nb1, part2, nb2, out, N, M);
  } else {
    float* acc = (float*)d_ws;
    (void)hipMemsetAsync(acc, 0, 6 * sizeof(float), stream);
    vertex_kernel<<<(N + BLOCK - 1) / BLOCK, BLOCK, 0, stream>>>(
        mp, grad, H, ngt, theta, u, v, rot, nbr, acc, N);
    point_kernel<<<(M + BLOCK - 1) / BLOCK, BLOCK, 0, stream>>>(npred, ngrad, acc, M);
    finalize_acc<<<1, 64, 0, stream>>>(acc, out, N, M);
  }
}